// Round 6
// baseline (138.747 us; speedup 1.0000x reference)
//
#include <hip/hip_runtime.h>
#include <hip/hip_bf16.h>
#include <stdint.h>

// Problem constants
#define BB 2
#define NN 2048
#define DIMM 1024
#define HEADS 16
#define DH 64
#define E3 3072   // 3*DIM
#define LOG2E_ 1.44269504088896f
#define THR_ 8.0f

typedef __bf16 bf16;
typedef __attribute__((ext_vector_type(8))) __bf16 bf16x8;
typedef __attribute__((ext_vector_type(4))) __bf16 bf16x4;
typedef __attribute__((ext_vector_type(4))) float f32x4;

// global -> LDS direct copy, 16B per lane. LDS dest must be wave-uniform base;
// HW adds lane*16. Global src is per-lane.
__device__ __forceinline__ void gload_lds16(const void* gsrc, void* ldst) {
  __builtin_amdgcn_global_load_lds(
      (const __attribute__((address_space(1))) uint32_t*)(uintptr_t)gsrc,
      (__attribute__((address_space(3))) uint32_t*)(uintptr_t)ldst,
      16, 0, 0);
}

// ---------------------------------------------------------------------------
// Kernel 1: fp32 -> bf16 conversion for x, w_qkv, w_out (fused)
// ---------------------------------------------------------------------------
__global__ __launch_bounds__(256)
void convert_all(const float* __restrict__ x, const float* __restrict__ wqkv,
                 const float* __restrict__ wout,
                 bf16* __restrict__ xb, bf16* __restrict__ wqb, bf16* __restrict__ wob) {
  size_t i = (size_t)blockIdx.x * blockDim.x + threadIdx.x;
  const float* src;
  bf16* dst;
  size_t off;
  if (i < 1048576u) { src = x; dst = xb; off = i; }
  else if (i < 1048576u + 786432u) { src = wqkv; dst = wqb; off = i - 1048576u; }
  else { src = wout; dst = wob; off = i - (1048576u + 786432u); }
  float4 v = ((const float4*)src)[off];
  bf16x4 o;
  o[0] = (bf16)v.x; o[1] = (bf16)v.y; o[2] = (bf16)v.z; o[3] = (bf16)v.w;
  *(bf16x4*)(dst + off * 4) = o;
}

// ---------------------------------------------------------------------------
// Kernel 2/4: C[m][n] = sum_k A[m][k] * Bw[n][k]   (B^T-input GEMM), K = 1024
// OUTMODE 0: bf16 store (qkv), Q columns (n<1024) pre-scaled by 0.125 (exact).
// OUTMODE 1: f32 store + bias (final output).
// ---------------------------------------------------------------------------
template <int OUTMODE>
__global__ __launch_bounds__(256)
void gemm_bt(const bf16* __restrict__ A, const bf16* __restrict__ Bw,
             void* __restrict__ Cout, const float* __restrict__ bias, int ldc) {
  const int tid = threadIdx.x;
  const int w = tid >> 6;
  const int lane = tid & 63;
  const int c = lane & 15;
  const int g = lane >> 4;
  const int wr = w >> 1, wc = w & 1;
  const int m0 = blockIdx.y * 128;
  const int n0 = blockIdx.x * 128;

  __shared__ __align__(16) char smem[16384];
  char* As = smem;
  char* Bs = smem + 8192;

  f32x4 acc[4][4] = {};

  for (int kt = 0; kt < 1024; kt += 32) {
    __syncthreads();
#pragma unroll
    for (int it = 0; it < 2; ++it) {
      int t = it * 256 + tid;
      int row = t >> 2, cc = t & 3;
      gload_lds16(A + (size_t)(m0 + row) * 1024 + kt + cc * 8, As + it * 4096 + w * 1024);
      gload_lds16(Bw + (size_t)(n0 + row) * 1024 + kt + cc * 8, Bs + it * 4096 + w * 1024);
    }
    __syncthreads();

    bf16x8 af[4], bfr[4];
#pragma unroll
    for (int i = 0; i < 4; ++i)
      af[i] = *(const bf16x8*)(As + ((wr * 64 + i * 16 + c) * 32 + g * 8) * 2);
#pragma unroll
    for (int j = 0; j < 4; ++j)
      bfr[j] = *(const bf16x8*)(Bs + ((wc * 64 + j * 16 + c) * 32 + g * 8) * 2);
#pragma unroll
    for (int i = 0; i < 4; ++i)
#pragma unroll
      for (int j = 0; j < 4; ++j)
        acc[i][j] = __builtin_amdgcn_mfma_f32_16x16x32_bf16(af[i], bfr[j], acc[i][j], 0, 0, 0);
  }

  if (OUTMODE == 0) {
    const float qsc = (n0 < 1024) ? 0.125f : 1.0f;
    bf16* C = (bf16*)Cout;
#pragma unroll
    for (int i = 0; i < 4; ++i) {
      int row = m0 + wr * 64 + i * 16 + g * 4;
#pragma unroll
      for (int j = 0; j < 4; ++j) {
        int col = n0 + wc * 64 + j * 16 + c;
#pragma unroll
        for (int r = 0; r < 4; ++r)
          C[(size_t)(row + r) * ldc + col] = (bf16)(acc[i][j][r] * qsc);
      }
    }
  } else {
    float* C = (float*)Cout;
#pragma unroll
    for (int i = 0; i < 4; ++i) {
      int row = m0 + wr * 64 + i * 16 + g * 4;
#pragma unroll
      for (int j = 0; j < 4; ++j) {
        int col = n0 + wc * 64 + j * 16 + c;
        float bv = bias[col];
#pragma unroll
        for (int r = 0; r < 4; ++r)
          C[(size_t)(row + r) * ldc + col] = acc[i][j][r] + bv;
      }
    }
  }
}

// ---------------------------------------------------------------------------
// Kernel 3: fused flash attention — swapped-operand (S^T / O^T) form.
// Round 6: 4 waves/block x 32 q-rows/wave = 128 q-rows/block, grid 512.
// Halves LDS read bytes per q-row (K/V tile read once per wave, used by
// 2 qcol tiles). Same 32KB LDS, same staging, same numerics as round 5.
//   Ks[2] @0/@8192   : [64 row][8 chunk of 16B], chunk XOR-swizzled (rule 21)
//   Vs[2] @16384/@24576 : tr-read subtile layout (see staging decode)
// QK^T swapped: sacc = mfma(K, Q): lane (c,g) holds S^T[key=16j+4g+r][q=c].
// PV B-frag word jj of vb[ks] = p[2*(jj>>2)+ks][jj&3] (g-independent).
// Softmax in log2 units; T13 defer-rescale; l via MFMA row-sum.
// ---------------------------------------------------------------------------
__global__ __launch_bounds__(256, 4)
void flash_attn(const bf16* __restrict__ qkv, bf16* __restrict__ attb) {
  int bid = blockIdx.x;
  bid = (bid & 7) * 64 + (bid >> 3);  // XCD chunk swizzle (512 % 8 == 0)
  const int tid = threadIdx.x;
  const int w = tid >> 6;
  const int lane = tid & 63;
  const int c = lane & 15;
  const int g = lane >> 4;
  const int qt = bid & 15;            // 16 q-tiles of 128 rows
  const int bh = bid >> 4;
  const int b = bh >> 4;
  const int h = bh & 15;
  const int q0 = qt * 128 + w * 32;

  __shared__ __align__(16) char smem[32768];
  const uint32_t smem32 = (uint32_t)(uintptr_t)smem;

  // Q B-frags (2 qcol tiles per wave): lane holds Q[q=q0+qc*16+c][d=kd*32+g*8..]
  bf16x8 qf[2][2];
#pragma unroll
  for (int qc = 0; qc < 2; ++qc) {
    const size_t qbase = (size_t)(b * NN + q0 + qc * 16 + c) * E3 + h * 64;
    qf[qc][0] = *(const bf16x8*)(qkv + qbase + g * 8);
    qf[qc][1] = *(const bf16x8*)(qkv + qbase + 32 + g * 8);
  }

  // ones A-fragment for the l row-sum MFMA
  bf16x8 ones;
#pragma unroll
  for (int e = 0; e < 8; ++e) ones[e] = (bf16)1.0f;

  // Staging: 2 K issues + 2 V issues per tile, 256 threads x 16B each.
  const bf16 *pK0, *pK1, *pV0, *pV1;
  {
    int tK0 = tid, tK1 = 256 + tid;
    int r0 = tK0 >> 3, s0 = (tK0 & 7) ^ (r0 & 7);
    int r1 = tK1 >> 3, s1 = (tK1 & 7) ^ (r1 & 7);
    pK0 = qkv + (size_t)(b * NN + r0) * E3 + 1024 + h * 64 + s0 * 8;
    pK1 = qkv + (size_t)(b * NN + r1) * E3 + 1024 + h * 64 + s1 * 8;
    int sv0 = tid, sv1 = 256 + tid;
    int f0 = sv0 >> 7, ks0 = (sv0 >> 6) & 1, o0 = (sv0 >> 5) & 1,
        g0 = (sv0 >> 3) & 3, j0 = (sv0 >> 1) & 3, i0 = sv0 & 1;
    int f1 = sv1 >> 7, ks1 = (sv1 >> 6) & 1, o1 = (sv1 >> 5) & 1,
        g1 = (sv1 >> 3) & 3, j1 = (sv1 >> 1) & 3, i1 = sv1 & 1;
    int key0 = 32 * o0 + 16 * ks0 + 4 * g0 + j0;
    int key1 = 32 * o1 + 16 * ks1 + 4 * g1 + j1;
    pV0 = qkv + (size_t)(b * NN + key0) * E3 + 2048 + h * 64 + f0 * 16 + i0 * 8;
    pV1 = qkv + (size_t)(b * NN + key1) * E3 + 2048 + h * 64 + f1 * 16 + i1 * 8;
  }

  f32x4 oacc[4][2] = {};
  f32x4 lacc[2] = {};
  float mrun[2] = {-1e30f, -1e30f};

  // prologue: stage tile 0 into buf 0
  gload_lds16(pK0, smem + w * 1024);
  gload_lds16(pK1, smem + 4096 + w * 1024);
  gload_lds16(pV0, smem + 16384 + w * 1024);
  gload_lds16(pV1, smem + 16384 + 4096 + w * 1024);
  pK0 += 64 * E3; pK1 += 64 * E3; pV0 += 64 * E3; pV1 += 64 * E3;
  __syncthreads();

  int buf = 0;
  for (int t = 0; t < 32; ++t) {
    if (t < 31) {
      const int o = (buf ^ 1) * 8192;
      gload_lds16(pK0, smem + o + w * 1024);
      gload_lds16(pK1, smem + o + 4096 + w * 1024);
      gload_lds16(pV0, smem + 16384 + o + w * 1024);
      gload_lds16(pV1, smem + 16384 + o + 4096 + w * 1024);
      pK0 += 64 * E3; pK1 += 64 * E3; pV0 += 64 * E3; pV1 += 64 * E3;
    }

    const char* KsP = smem + buf * 8192;
    const uint32_t vaddr = smem32 + 16384 + buf * 8192 + lane * 8;

    // QK^T swapped: sacc[j][qc] = S^T (lane: keys 16j+4g+r for q=qc*16+c)
    f32x4 sacc[4][2] = {};
    __builtin_amdgcn_s_setprio(1);
#pragma unroll
    for (int j = 0; j < 4; ++j) {
      const int row = j * 16 + c;
#pragma unroll
      for (int kd = 0; kd < 2; ++kd) {
        bf16x8 kf = *(const bf16x8*)(KsP + row * 128 + (((kd * 4 + g) ^ (c & 7)) * 16));
        sacc[j][0] = __builtin_amdgcn_mfma_f32_16x16x32_bf16(kf, qf[0][kd], sacc[j][0], 0, 0, 0);
        sacc[j][1] = __builtin_amdgcn_mfma_f32_16x16x32_bf16(kf, qf[1][kd], sacc[j][1], 0, 0, 0);
      }
    }
    __builtin_amdgcn_s_setprio(0);

    // issue all 16 V transpose-reads (consumed by both qcol PV phases)
    bf16x4 tlo[4][2], thi[4][2];
#pragma unroll
    for (int f = 0; f < 4; ++f)
#pragma unroll
      for (int ks = 0; ks < 2; ++ks) {
        asm volatile("ds_read_b64_tr_b16 %0, %1 offset:%c2"
                     : "=v"(tlo[f][ks]) : "v"(vaddr), "i"(f * 2048 + ks * 1024));
        asm volatile("ds_read_b64_tr_b16 %0, %1 offset:%c2"
                     : "=v"(thi[f][ks]) : "v"(vaddr), "i"(f * 2048 + ks * 1024 + 512));
      }

#pragma unroll
    for (int qc = 0; qc < 2; ++qc) {
      // raw-S row max (max commutes with the positive LOG2E scale)
      f32x4 vm = sacc[0][qc];
#pragma unroll
      for (int j = 1; j < 4; ++j)
#pragma unroll
        for (int r = 0; r < 4; ++r) vm[r] = fmaxf(vm[r], sacc[j][qc][r]);
      float rmax = fmaxf(fmaxf(vm[0], vm[1]), fmaxf(vm[2], vm[3]));
      rmax = fmaxf(rmax, __shfl_xor(rmax, 16, 64));
      rmax = fmaxf(rmax, __shfl_xor(rmax, 32, 64));
      const float rmax2 = rmax * LOG2E_;

      // T13 defer-rescale: only rescale when the running max grew by > THR
      if (!__all(rmax2 <= mrun[qc] + THR_)) {
        const float mnew = fmaxf(mrun[qc], rmax2);
        const float fac = __builtin_amdgcn_exp2f(mrun[qc] - mnew);
        mrun[qc] = mnew;
#pragma unroll
        for (int f = 0; f < 4; ++f) oacc[f][qc] *= fac;
        lacc[qc] *= fac;
      }
      const float negm = -mrun[qc];

      // p = exp2(fma(s, LOG2E, -m)), bounded by 2^THR
      f32x4 p[4];
#pragma unroll
      for (int j = 0; j < 4; ++j)
#pragma unroll
        for (int r = 0; r < 4; ++r)
          p[j][r] = __builtin_amdgcn_exp2f(fmaf(sacc[j][qc][r], LOG2E_, negm));

      // PV B-frags: word jj of vb[ks] = p[2*(jj>>2)+ks][jj&3]  (g-independent)
      bf16x8 vb[2];
#pragma unroll
      for (int ks = 0; ks < 2; ++ks)
#pragma unroll
        for (int r = 0; r < 4; ++r) {
          vb[ks][r] = (bf16)p[ks][r];
          vb[ks][4 + r] = (bf16)p[ks + 2][r];
        }

      if (qc == 0) {  // tr-reads must have landed before first PV use
        asm volatile("s_waitcnt lgkmcnt(0)" ::: "memory");
        __builtin_amdgcn_sched_barrier(0);
      }

      __builtin_amdgcn_s_setprio(1);
#pragma unroll
      for (int f = 0; f < 4; ++f)
#pragma unroll
        for (int ks = 0; ks < 2; ++ks) {
          bf16x8 va;
#pragma unroll
          for (int e = 0; e < 4; ++e) { va[e] = tlo[f][ks][e]; va[4 + e] = thi[f][ks][e]; }
          oacc[f][qc] = __builtin_amdgcn_mfma_f32_16x16x32_bf16(va, vb[ks], oacc[f][qc], 0, 0, 0);
        }
      // l row-sum on the MFMA pipe (all 16 output rows identical = per-q sum)
      lacc[qc] = __builtin_amdgcn_mfma_f32_16x16x32_bf16(ones, vb[0], lacc[qc], 0, 0, 0);
      lacc[qc] = __builtin_amdgcn_mfma_f32_16x16x32_bf16(ones, vb[1], lacc[qc], 0, 0, 0);
      __builtin_amdgcn_s_setprio(0);
    }

    __syncthreads();  // drains staging vmcnt + lgkm; swaps buffers
    buf ^= 1;
  }

  // epilogue: O^T -> attb[row=q][col=h*64+d]; lane holds d = f*16+4g+r, q = q0+qc*16+c
#pragma unroll
  for (int qc = 0; qc < 2; ++qc) {
    const float inv = __builtin_amdgcn_rcpf(lacc[qc][0]);
    const size_t row = (size_t)(b * NN + q0 + qc * 16 + c);
#pragma unroll
    for (int f = 0; f < 4; ++f) {
      bf16x4 o;
#pragma unroll
      for (int r = 0; r < 4; ++r) o[r] = (bf16)(oacc[f][qc][r] * inv);
      *(bf16x4*)(attb + row * 1024 + h * 64 + f * 16 + 4 * g) = o;
    }
  }
}

// ---------------------------------------------------------------------------
extern "C" void kernel_launch(void* const* d_in, const int* in_sizes, int n_in,
                              void* d_out, int out_size, void* d_ws, size_t ws_size,
                              hipStream_t stream) {
  const float* x = (const float*)d_in[0];
  const float* wqkv = (const float*)d_in[1];
  const float* wout = (const float*)d_in[2];
  const float* bout = (const float*)d_in[3];

  char* ws = (char*)d_ws;
  bf16* xb   = (bf16*)(ws);
  bf16* wqb  = (bf16*)(ws + 8388608);
  bf16* wob  = (bf16*)(ws + 14680064);
  bf16* qkvb = (bf16*)(ws + 16777216);
  bf16* attb = (bf16*)(ws + 41943040);

  convert_all<<<8192, 256, 0, stream>>>(x, wqkv, wout, xb, wqb, wob);
  gemm_bt<0><<<dim3(24, 32), 256, 0, stream>>>(xb, wqb, (void*)qkvb, nullptr, E3);
  flash_attn<<<512, 256, 0, stream>>>(qkvb, attb);
  gemm_bt<1><<<dim3(8, 32), 256, 0, stream>>>(attb, wob, d_out, bout, DIMM);
}

// Round 7
// 114.364 us; speedup vs baseline: 1.2132x; 1.2132x over previous
//
#include <hip/hip_runtime.h>
#include <hip/hip_bf16.h>
#include <stdint.h>

// Problem constants
#define BB 2
#define NN 2048
#define DIMM 1024
#define HEADS 16
#define DH 64
#define E3 3072   // 3*DIM
#define LOG2E_ 1.44269504088896f
#define THR_ 8.0f

typedef __bf16 bf16;
typedef __attribute__((ext_vector_type(8))) __bf16 bf16x8;
typedef __attribute__((ext_vector_type(4))) __bf16 bf16x4;
typedef __attribute__((ext_vector_type(4))) float f32x4;

// global -> LDS direct copy, 16B per lane. LDS dest must be wave-uniform base;
// HW adds lane*16. Global src is per-lane.
__device__ __forceinline__ void gload_lds16(const void* gsrc, void* ldst) {
  __builtin_amdgcn_global_load_lds(
      (const __attribute__((address_space(1))) uint32_t*)(uintptr_t)gsrc,
      (__attribute__((address_space(3))) uint32_t*)(uintptr_t)ldst,
      16, 0, 0);
}

// ---------------------------------------------------------------------------
// Kernel 1: fp32 -> bf16 conversion for x, w_qkv, w_out (fused)
// ---------------------------------------------------------------------------
__global__ __launch_bounds__(256)
void convert_all(const float* __restrict__ x, const float* __restrict__ wqkv,
                 const float* __restrict__ wout,
                 bf16* __restrict__ xb, bf16* __restrict__ wqb, bf16* __restrict__ wob) {
  size_t i = (size_t)blockIdx.x * blockDim.x + threadIdx.x;
  const float* src;
  bf16* dst;
  size_t off;
  if (i < 1048576u) { src = x; dst = xb; off = i; }
  else if (i < 1048576u + 786432u) { src = wqkv; dst = wqb; off = i - 1048576u; }
  else { src = wout; dst = wob; off = i - (1048576u + 786432u); }
  float4 v = ((const float4*)src)[off];
  bf16x4 o;
  o[0] = (bf16)v.x; o[1] = (bf16)v.y; o[2] = (bf16)v.z; o[3] = (bf16)v.w;
  *(bf16x4*)(dst + off * 4) = o;
}

// ---------------------------------------------------------------------------
// Kernel 2/4: C[m][n] = sum_k A[m][k] * Bw[n][k]   (B^T-input GEMM), K = 1024
// OUTMODE 0: bf16 store (qkv), Q columns (n<1024) pre-scaled by 0.125 (exact).
// OUTMODE 1: f32 store + bias (final output).
// ---------------------------------------------------------------------------
template <int OUTMODE>
__global__ __launch_bounds__(256)
void gemm_bt(const bf16* __restrict__ A, const bf16* __restrict__ Bw,
             void* __restrict__ Cout, const float* __restrict__ bias, int ldc) {
  const int tid = threadIdx.x;
  const int w = tid >> 6;
  const int lane = tid & 63;
  const int c = lane & 15;
  const int g = lane >> 4;
  const int wr = w >> 1, wc = w & 1;
  const int m0 = blockIdx.y * 128;
  const int n0 = blockIdx.x * 128;

  __shared__ __align__(16) char smem[16384];
  char* As = smem;
  char* Bs = smem + 8192;

  f32x4 acc[4][4] = {};

  for (int kt = 0; kt < 1024; kt += 32) {
    __syncthreads();
#pragma unroll
    for (int it = 0; it < 2; ++it) {
      int t = it * 256 + tid;
      int row = t >> 2, cc = t & 3;
      gload_lds16(A + (size_t)(m0 + row) * 1024 + kt + cc * 8, As + it * 4096 + w * 1024);
      gload_lds16(Bw + (size_t)(n0 + row) * 1024 + kt + cc * 8, Bs + it * 4096 + w * 1024);
    }
    __syncthreads();

    bf16x8 af[4], bfr[4];
#pragma unroll
    for (int i = 0; i < 4; ++i)
      af[i] = *(const bf16x8*)(As + ((wr * 64 + i * 16 + c) * 32 + g * 8) * 2);
#pragma unroll
    for (int j = 0; j < 4; ++j)
      bfr[j] = *(const bf16x8*)(Bs + ((wc * 64 + j * 16 + c) * 32 + g * 8) * 2);
#pragma unroll
    for (int i = 0; i < 4; ++i)
#pragma unroll
      for (int j = 0; j < 4; ++j)
        acc[i][j] = __builtin_amdgcn_mfma_f32_16x16x32_bf16(af[i], bfr[j], acc[i][j], 0, 0, 0);
  }

  if (OUTMODE == 0) {
    const float qsc = (n0 < 1024) ? 0.125f : 1.0f;
    bf16* C = (bf16*)Cout;
#pragma unroll
    for (int i = 0; i < 4; ++i) {
      int row = m0 + wr * 64 + i * 16 + g * 4;
#pragma unroll
      for (int j = 0; j < 4; ++j) {
        int col = n0 + wc * 64 + j * 16 + c;
#pragma unroll
        for (int r = 0; r < 4; ++r)
          C[(size_t)(row + r) * ldc + col] = (bf16)(acc[i][j][r] * qsc);
      }
    }
  } else {
    float* C = (float*)Cout;
#pragma unroll
    for (int i = 0; i < 4; ++i) {
      int row = m0 + wr * 64 + i * 16 + g * 4;
#pragma unroll
      for (int j = 0; j < 4; ++j) {
        int col = n0 + wc * 64 + j * 16 + c;
        float bv = bias[col];
#pragma unroll
        for (int r = 0; r < 4; ++r)
          C[(size_t)(row + r) * ldc + col] = acc[i][j][r] + bv;
      }
    }
  }
}

// ---------------------------------------------------------------------------
// Kernel 3: fused flash attention — swapped-operand (S^T / O^T) form.
// Round 7: same structure as round 6 (4 waves x 32 q-rows, grid 512) but
// __launch_bounds__(256, 3): round 6's (256,4) made the allocator clamp to
// 64 VGPR and spill ~13MB/dispatch to scratch (WRITE_SIZE 8.2->16.9MB).
// Cap ~168 VGPR fits the ~120-reg live set with zero spill.
//   Ks[2] @0/@8192   : [64 row][8 chunk of 16B], chunk XOR-swizzled (rule 21)
//   Vs[2] @16384/@24576 : tr-read subtile layout (see staging decode)
// QK^T swapped: sacc = mfma(K, Q): lane (c,g) holds S^T[key=16j+4g+r][q=c].
// PV B-frag word jj of vb[ks] = p[2*(jj>>2)+ks][jj&3] (g-independent).
// Softmax in log2 units; T13 defer-rescale; l via MFMA row-sum.
// ---------------------------------------------------------------------------
__global__ __launch_bounds__(256, 3)
void flash_attn(const bf16* __restrict__ qkv, bf16* __restrict__ attb) {
  int bid = blockIdx.x;
  bid = (bid & 7) * 64 + (bid >> 3);  // XCD chunk swizzle (512 % 8 == 0)
  const int tid = threadIdx.x;
  const int w = tid >> 6;
  const int lane = tid & 63;
  const int c = lane & 15;
  const int g = lane >> 4;
  const int qt = bid & 15;            // 16 q-tiles of 128 rows
  const int bh = bid >> 4;
  const int b = bh >> 4;
  const int h = bh & 15;
  const int q0 = qt * 128 + w * 32;

  __shared__ __align__(16) char smem[32768];
  const uint32_t smem32 = (uint32_t)(uintptr_t)smem;

  // Q B-frags (2 qcol tiles per wave): lane holds Q[q=q0+qc*16+c][d=kd*32+g*8..]
  bf16x8 qf[2][2];
#pragma unroll
  for (int qc = 0; qc < 2; ++qc) {
    const size_t qbase = (size_t)(b * NN + q0 + qc * 16 + c) * E3 + h * 64;
    qf[qc][0] = *(const bf16x8*)(qkv + qbase + g * 8);
    qf[qc][1] = *(const bf16x8*)(qkv + qbase + 32 + g * 8);
  }

  // ones A-fragment for the l row-sum MFMA
  bf16x8 ones;
#pragma unroll
  for (int e = 0; e < 8; ++e) ones[e] = (bf16)1.0f;

  // Staging: 2 K issues + 2 V issues per tile, 256 threads x 16B each.
  const bf16 *pK0, *pK1, *pV0, *pV1;
  {
    int tK0 = tid, tK1 = 256 + tid;
    int r0 = tK0 >> 3, s0 = (tK0 & 7) ^ (r0 & 7);
    int r1 = tK1 >> 3, s1 = (tK1 & 7) ^ (r1 & 7);
    pK0 = qkv + (size_t)(b * NN + r0) * E3 + 1024 + h * 64 + s0 * 8;
    pK1 = qkv + (size_t)(b * NN + r1) * E3 + 1024 + h * 64 + s1 * 8;
    int sv0 = tid, sv1 = 256 + tid;
    int f0 = sv0 >> 7, ks0 = (sv0 >> 6) & 1, o0 = (sv0 >> 5) & 1,
        g0 = (sv0 >> 3) & 3, j0 = (sv0 >> 1) & 3, i0 = sv0 & 1;
    int f1 = sv1 >> 7, ks1 = (sv1 >> 6) & 1, o1 = (sv1 >> 5) & 1,
        g1 = (sv1 >> 3) & 3, j1 = (sv1 >> 1) & 3, i1 = sv1 & 1;
    int key0 = 32 * o0 + 16 * ks0 + 4 * g0 + j0;
    int key1 = 32 * o1 + 16 * ks1 + 4 * g1 + j1;
    pV0 = qkv + (size_t)(b * NN + key0) * E3 + 2048 + h * 64 + f0 * 16 + i0 * 8;
    pV1 = qkv + (size_t)(b * NN + key1) * E3 + 2048 + h * 64 + f1 * 16 + i1 * 8;
  }

  f32x4 oacc[4][2] = {};
  f32x4 lacc[2] = {};
  float mrun[2] = {-1e30f, -1e30f};

  // prologue: stage tile 0 into buf 0
  gload_lds16(pK0, smem + w * 1024);
  gload_lds16(pK1, smem + 4096 + w * 1024);
  gload_lds16(pV0, smem + 16384 + w * 1024);
  gload_lds16(pV1, smem + 16384 + 4096 + w * 1024);
  pK0 += 64 * E3; pK1 += 64 * E3; pV0 += 64 * E3; pV1 += 64 * E3;
  __syncthreads();

  int buf = 0;
  for (int t = 0; t < 32; ++t) {
    if (t < 31) {
      const int o = (buf ^ 1) * 8192;
      gload_lds16(pK0, smem + o + w * 1024);
      gload_lds16(pK1, smem + o + 4096 + w * 1024);
      gload_lds16(pV0, smem + 16384 + o + w * 1024);
      gload_lds16(pV1, smem + 16384 + o + 4096 + w * 1024);
      pK0 += 64 * E3; pK1 += 64 * E3; pV0 += 64 * E3; pV1 += 64 * E3;
    }

    const char* KsP = smem + buf * 8192;
    const uint32_t vaddr = smem32 + 16384 + buf * 8192 + lane * 8;

    // QK^T swapped: sacc[j][qc] = S^T (lane: keys 16j+4g+r for q=qc*16+c)
    f32x4 sacc[4][2] = {};
    __builtin_amdgcn_s_setprio(1);
#pragma unroll
    for (int j = 0; j < 4; ++j) {
      const int row = j * 16 + c;
#pragma unroll
      for (int kd = 0; kd < 2; ++kd) {
        bf16x8 kf = *(const bf16x8*)(KsP + row * 128 + (((kd * 4 + g) ^ (c & 7)) * 16));
        sacc[j][0] = __builtin_amdgcn_mfma_f32_16x16x32_bf16(kf, qf[0][kd], sacc[j][0], 0, 0, 0);
        sacc[j][1] = __builtin_amdgcn_mfma_f32_16x16x32_bf16(kf, qf[1][kd], sacc[j][1], 0, 0, 0);
      }
    }
    __builtin_amdgcn_s_setprio(0);

    // issue all 16 V transpose-reads (consumed by both qcol PV phases)
    bf16x4 tlo[4][2], thi[4][2];
#pragma unroll
    for (int f = 0; f < 4; ++f)
#pragma unroll
      for (int ks = 0; ks < 2; ++ks) {
        asm volatile("ds_read_b64_tr_b16 %0, %1 offset:%c2"
                     : "=v"(tlo[f][ks]) : "v"(vaddr), "i"(f * 2048 + ks * 1024));
        asm volatile("ds_read_b64_tr_b16 %0, %1 offset:%c2"
                     : "=v"(thi[f][ks]) : "v"(vaddr), "i"(f * 2048 + ks * 1024 + 512));
      }

#pragma unroll
    for (int qc = 0; qc < 2; ++qc) {
      // raw-S row max (max commutes with the positive LOG2E scale)
      f32x4 vm = sacc[0][qc];
#pragma unroll
      for (int j = 1; j < 4; ++j)
#pragma unroll
        for (int r = 0; r < 4; ++r) vm[r] = fmaxf(vm[r], sacc[j][qc][r]);
      float rmax = fmaxf(fmaxf(vm[0], vm[1]), fmaxf(vm[2], vm[3]));
      rmax = fmaxf(rmax, __shfl_xor(rmax, 16, 64));
      rmax = fmaxf(rmax, __shfl_xor(rmax, 32, 64));
      const float rmax2 = rmax * LOG2E_;

      // T13 defer-rescale: only rescale when the running max grew by > THR
      if (!__all(rmax2 <= mrun[qc] + THR_)) {
        const float mnew = fmaxf(mrun[qc], rmax2);
        const float fac = __builtin_amdgcn_exp2f(mrun[qc] - mnew);
        mrun[qc] = mnew;
#pragma unroll
        for (int f = 0; f < 4; ++f) oacc[f][qc] *= fac;
        lacc[qc] *= fac;
      }
      const float negm = -mrun[qc];

      // p = exp2(fma(s, LOG2E, -m)), bounded by 2^THR
      f32x4 p[4];
#pragma unroll
      for (int j = 0; j < 4; ++j)
#pragma unroll
        for (int r = 0; r < 4; ++r)
          p[j][r] = __builtin_amdgcn_exp2f(fmaf(sacc[j][qc][r], LOG2E_, negm));

      // PV B-frags: word jj of vb[ks] = p[2*(jj>>2)+ks][jj&3]  (g-independent)
      bf16x8 vb[2];
#pragma unroll
      for (int ks = 0; ks < 2; ++ks)
#pragma unroll
        for (int r = 0; r < 4; ++r) {
          vb[ks][r] = (bf16)p[ks][r];
          vb[ks][4 + r] = (bf16)p[ks + 2][r];
        }

      if (qc == 0) {  // tr-reads must have landed before first PV use
        asm volatile("s_waitcnt lgkmcnt(0)" ::: "memory");
        __builtin_amdgcn_sched_barrier(0);
      }

      __builtin_amdgcn_s_setprio(1);
#pragma unroll
      for (int f = 0; f < 4; ++f)
#pragma unroll
        for (int ks = 0; ks < 2; ++ks) {
          bf16x8 va;
#pragma unroll
          for (int e = 0; e < 4; ++e) { va[e] = tlo[f][ks][e]; va[4 + e] = thi[f][ks][e]; }
          oacc[f][qc] = __builtin_amdgcn_mfma_f32_16x16x32_bf16(va, vb[ks], oacc[f][qc], 0, 0, 0);
        }
      // l row-sum on the MFMA pipe (all 16 output rows identical = per-q sum)
      lacc[qc] = __builtin_amdgcn_mfma_f32_16x16x32_bf16(ones, vb[0], lacc[qc], 0, 0, 0);
      lacc[qc] = __builtin_amdgcn_mfma_f32_16x16x32_bf16(ones, vb[1], lacc[qc], 0, 0, 0);
      __builtin_amdgcn_s_setprio(0);
    }

    __syncthreads();  // drains staging vmcnt + lgkm; swaps buffers
    buf ^= 1;
  }

  // epilogue: O^T -> attb[row=q][col=h*64+d]; lane holds d = f*16+4g+r, q = q0+qc*16+c
#pragma unroll
  for (int qc = 0; qc < 2; ++qc) {
    const float inv = __builtin_amdgcn_rcpf(lacc[qc][0]);
    const size_t row = (size_t)(b * NN + q0 + qc * 16 + c);
#pragma unroll
    for (int f = 0; f < 4; ++f) {
      bf16x4 o;
#pragma unroll
      for (int r = 0; r < 4; ++r) o[r] = (bf16)(oacc[f][qc][r] * inv);
      *(bf16x4*)(attb + row * 1024 + h * 64 + f * 16 + 4 * g) = o;
    }
  }
}

// ---------------------------------------------------------------------------
extern "C" void kernel_launch(void* const* d_in, const int* in_sizes, int n_in,
                              void* d_out, int out_size, void* d_ws, size_t ws_size,
                              hipStream_t stream) {
  const float* x = (const float*)d_in[0];
  const float* wqkv = (const float*)d_in[1];
  const float* wout = (const float*)d_in[2];
  const float* bout = (const float*)d_in[3];

  char* ws = (char*)d_ws;
  bf16* xb   = (bf16*)(ws);
  bf16* wqb  = (bf16*)(ws + 8388608);
  bf16* wob  = (bf16*)(ws + 14680064);
  bf16* qkvb = (bf16*)(ws + 16777216);
  bf16* attb = (bf16*)(ws + 41943040);

  convert_all<<<8192, 256, 0, stream>>>(x, wqkv, wout, xb, wqb, wob);
  gemm_bt<0><<<dim3(24, 32), 256, 0, stream>>>(xb, wqb, (void*)qkvb, nullptr, E3);
  flash_attn<<<512, 256, 0, stream>>>(qkvb, attb);
  gemm_bt<1><<<dim3(8, 32), 256, 0, stream>>>(attb, wob, d_out, bout, DIMM);
}